// Round 1
// baseline (422.788 us; speedup 1.0000x reference)
//
#include <hip/hip_runtime.h>
#include <hip/hip_fp16.h>

using f32x4 = __attribute__((ext_vector_type(4))) float;
using f16x8 = __attribute__((ext_vector_type(8))) _Float16;

constexpr int K_DIM = 4096;   // N_IN
constexpr int N_DIM = 4096;   // N_OUT
constexpr float QBf = 128.0f;
constexpr float EPf = 0.01f;
constexpr float LN_EPSf = 1e-5f;

#define GLOAD_LDS16(gp, lp)                                                  \
    __builtin_amdgcn_global_load_lds(                                        \
        (const __attribute__((address_space(1))) void*)(gp),                 \
        (__attribute__((address_space(3))) void*)(lp), 16, 0, 0)

// ---------------------------------------------------------------------------
// Kernel 1: fused LayerNorm + ABSMax-quant + fp16 cast.  One block per row.
// ---------------------------------------------------------------------------
__global__ __launch_bounds__(256) void ln_quant_kernel(
    const float* __restrict__ x,
    const float* __restrict__ ln_g,
    const float* __restrict__ ln_b,
    const float* __restrict__ gamma_p,
    _Float16* __restrict__ xq)
{
    const int row = blockIdx.x;
    const int t = threadIdx.x;
    const float* xr = x + (size_t)row * K_DIM;

    float4 v[4];
    float sum = 0.f, sumsq = 0.f;
#pragma unroll
    for (int i = 0; i < 4; ++i) {
        v[i] = reinterpret_cast<const float4*>(xr)[i * 256 + t];
        sum += v[i].x + v[i].y + v[i].z + v[i].w;
        sumsq += v[i].x * v[i].x + v[i].y * v[i].y + v[i].z * v[i].z + v[i].w * v[i].w;
    }
#pragma unroll
    for (int off = 32; off > 0; off >>= 1) {
        sum += __shfl_down(sum, off);
        sumsq += __shfl_down(sumsq, off);
    }
    __shared__ float s_sum[4], s_sq[4];
    const int lane = t & 63, w = t >> 6;
    if (lane == 0) { s_sum[w] = sum; s_sq[w] = sumsq; }
    __syncthreads();
    sum = s_sum[0] + s_sum[1] + s_sum[2] + s_sum[3];
    sumsq = s_sq[0] + s_sq[1] + s_sq[2] + s_sq[3];

    const float mu = sum * (1.0f / K_DIM);
    const float var = sumsq * (1.0f / K_DIM) - mu * mu;
    const float rstd = rsqrtf(var + LN_EPSf);
    const float qs = QBf / gamma_p[0];
    const float lo = -QBf + EPf, hi = QBf - EPf;

    _Float16* xqr = xq + (size_t)row * K_DIM;
#pragma unroll
    for (int i = 0; i < 4; ++i) {
        const int idx = i * 256 + t;
        const float4 g = reinterpret_cast<const float4*>(ln_g)[idx];
        const float4 b = reinterpret_cast<const float4*>(ln_b)[idx];
        const float q0 = fminf(fmaxf(((v[i].x - mu) * rstd * g.x + b.x) * qs, lo), hi);
        const float q1 = fminf(fmaxf(((v[i].y - mu) * rstd * g.y + b.y) * qs, lo), hi);
        const float q2 = fminf(fmaxf(((v[i].z - mu) * rstd * g.z + b.z) * qs, lo), hi);
        const float q3 = fminf(fmaxf(((v[i].w - mu) * rstd * g.w + b.w) * qs, lo), hi);
        alignas(8) _Float16 h[4] = {(_Float16)q0, (_Float16)q1, (_Float16)q2, (_Float16)q3};
        *reinterpret_cast<uint2*>(xqr + (size_t)idx * 4) = *reinterpret_cast<const uint2*>(h);
    }
}

// ---------------------------------------------------------------------------
// Kernel 2: w (fp32, K x N, values ±1) -> wt (fp16, N x K).  64x64 LDS tiles.
// ---------------------------------------------------------------------------
__global__ __launch_bounds__(256) void wtrans_kernel(
    const float* __restrict__ w, _Float16* __restrict__ wt)
{
    __shared__ _Float16 tile[64][72];
    const int t = threadIdx.x;
    const int bk = blockIdx.y * 64;   // k tile base
    const int bn = blockIdx.x * 64;   // n tile base
#pragma unroll
    for (int i = 0; i < 4; ++i) {
        const int li = i * 1024 + t * 4;
        const int r = li >> 6, c = li & 63;
        const float4 vv = *reinterpret_cast<const float4*>(
            w + (size_t)(bk + r) * N_DIM + bn + c);
        tile[r][c]     = (_Float16)vv.x;
        tile[r][c + 1] = (_Float16)vv.y;
        tile[r][c + 2] = (_Float16)vv.z;
        tile[r][c + 3] = (_Float16)vv.w;
    }
    __syncthreads();
#pragma unroll
    for (int i = 0; i < 4; ++i) {
        const int li = i * 1024 + t * 4;
        const int r = li >> 6, c = li & 63;   // r = n-in-tile, c = k-in-tile
        alignas(8) _Float16 h[4] = {tile[c][r], tile[c + 1][r], tile[c + 2][r], tile[c + 3][r]};
        *reinterpret_cast<uint2*>(wt + (size_t)(bn + r) * K_DIM + bk + c) =
            *reinterpret_cast<const uint2*>(h);
    }
}

// ---------------------------------------------------------------------------
// Kernel 3: GEMM  C[M,N] = A[M,K] * Bt[N,K]^T  * scale  (fp16 MFMA, fp32 acc)
// 128x128 tile, BK=64, 4 waves, each wave 64x64 (4x4 of 16x16x32 fragments).
// m97 structure: global_load_lds width-16 staging, 2 barriers per K-step.
// ---------------------------------------------------------------------------
__global__ __launch_bounds__(256) void gemm_kernel(
    const _Float16* __restrict__ A,
    const _Float16* __restrict__ Bt,
    float* __restrict__ C,
    const float* __restrict__ beta_p,
    const float* __restrict__ gamma_p)
{
    constexpr int BK = 64;
    __shared__ _Float16 As[128 * BK];   // [m][k] linear, 16 KiB
    __shared__ _Float16 Bs[128 * BK];   // [n][k] linear, 16 KiB

    const int t = threadIdx.x;
    const int bm = blockIdx.y * 128;
    const int bn = blockIdx.x * 128;
    const int lane = t & 63;
    const int w = t >> 6;
    const int wr = (w >> 1) * 64;       // wave row offset in tile
    const int wc = (w & 1) * 64;        // wave col offset in tile
    const int fr = lane & 15;           // fragment row/col within 16
    const int kg = (lane >> 4) * 8;     // k-group offset (8 contiguous k per lane)

    f32x4 acc[4][4];
#pragma unroll
    for (int m = 0; m < 4; ++m)
#pragma unroll
        for (int n = 0; n < 4; ++n)
            acc[m][n] = (f32x4){0.f, 0.f, 0.f, 0.f};

    const _Float16* Abase = A + (size_t)bm * K_DIM;
    const _Float16* Bbase = Bt + (size_t)bn * K_DIM;

    for (int k0 = 0; k0 < K_DIM; k0 += BK) {
        // ---- stage A,B tiles: 1024 chunks of 16B each per matrix ----
#pragma unroll
        for (int i = 0; i < 4; ++i) {
            const int c = i * 256 + t;
            const int m = c >> 3;           // row within tile (k-inner layout)
            const int kc = (c & 7) * 8;     // k offset in halfs
            GLOAD_LDS16(Abase + (size_t)m * K_DIM + k0 + kc, As + c * 8);
            GLOAD_LDS16(Bbase + (size_t)m * K_DIM + k0 + kc, Bs + c * 8);
        }
        __syncthreads();   // compiler drains vmcnt before s_barrier

        // ---- compute: 2 K=32 slices, 16 MFMAs each ----
#pragma unroll
        for (int kk = 0; kk < 2; ++kk) {
            const int kb = kk * 32 + kg;
            f16x8 a_frag[4], b_frag[4];
#pragma unroll
            for (int m = 0; m < 4; ++m)
                a_frag[m] = *reinterpret_cast<const f16x8*>(As + (wr + m * 16 + fr) * BK + kb);
#pragma unroll
            for (int n = 0; n < 4; ++n)
                b_frag[n] = *reinterpret_cast<const f16x8*>(Bs + (wc + n * 16 + fr) * BK + kb);
#pragma unroll
            for (int m = 0; m < 4; ++m)
#pragma unroll
                for (int n = 0; n < 4; ++n)
                    acc[m][n] = __builtin_amdgcn_mfma_f32_16x16x32_f16(
                        a_frag[m], b_frag[n], acc[m][n], 0, 0, 0);
        }
        __syncthreads();
    }

    // ---- epilogue: scale + store.  C/D layout: col=lane&15, row=(lane>>4)*4+j
    const float scale = beta_p[0] * gamma_p[0] * (1.0f / QBf);
    const int ocol = bn + wc + fr;
    const int orow = bm + wr + (lane >> 4) * 4;
#pragma unroll
    for (int m = 0; m < 4; ++m) {
#pragma unroll
        for (int j = 0; j < 4; ++j) {
            float* crow = C + (size_t)(orow + m * 16 + j) * N_DIM + ocol;
#pragma unroll
            for (int n = 0; n < 4; ++n)
                crow[n * 16] = acc[m][n][j] * scale;
        }
    }
}

// ---------------------------------------------------------------------------
extern "C" void kernel_launch(void* const* d_in, const int* in_sizes, int n_in,
                              void* d_out, int out_size, void* d_ws, size_t ws_size,
                              hipStream_t stream)
{
    const float* x       = (const float*)d_in[0];
    const float* w       = (const float*)d_in[1];
    const float* ln_g    = (const float*)d_in[2];
    const float* ln_b    = (const float*)d_in[3];
    const float* beta_p  = (const float*)d_in[4];
    const float* gamma_p = (const float*)d_in[5];
    float* out = (float*)d_out;

    const int M = in_sizes[0] / K_DIM;   // 8192

    _Float16* xq = (_Float16*)d_ws;
    _Float16* wt = (_Float16*)((char*)d_ws + (size_t)M * K_DIM * sizeof(_Float16));

    ln_quant_kernel<<<M, 256, 0, stream>>>(x, ln_g, ln_b, gamma_p, xq);
    wtrans_kernel<<<dim3(N_DIM / 64, K_DIM / 64), 256, 0, stream>>>(w, wt);
    gemm_kernel<<<dim3(N_DIM / 128, M / 128), 256, 0, stream>>>(xq, wt, out, beta_p, gamma_p);
}

// Round 2
// 359.708 us; speedup vs baseline: 1.1754x; 1.1754x over previous
//
#include <hip/hip_runtime.h>
#include <hip/hip_fp16.h>

using f32x4 = __attribute__((ext_vector_type(4))) float;
using f16x8 = __attribute__((ext_vector_type(8))) _Float16;

constexpr int K_DIM = 4096;   // N_IN
constexpr int N_DIM = 4096;   // N_OUT
constexpr float QBf = 128.0f;
constexpr float EPf = 0.01f;
constexpr float LN_EPSf = 1e-5f;

#define GLOAD_LDS16(gp, lp)                                                  \
    __builtin_amdgcn_global_load_lds(                                        \
        (const __attribute__((address_space(1))) void*)(gp),                 \
        (__attribute__((address_space(3))) void*)(lp), 16, 0, 0)

// ---------------------------------------------------------------------------
// Kernel 1: fused LayerNorm + ABSMax-quant + fp16 cast.  One block per row.
// ---------------------------------------------------------------------------
__global__ __launch_bounds__(256) void ln_quant_kernel(
    const float* __restrict__ x,
    const float* __restrict__ ln_g,
    const float* __restrict__ ln_b,
    const float* __restrict__ gamma_p,
    _Float16* __restrict__ xq)
{
    const int row = blockIdx.x;
    const int t = threadIdx.x;
    const float* xr = x + (size_t)row * K_DIM;

    float4 v[4];
    float sum = 0.f, sumsq = 0.f;
#pragma unroll
    for (int i = 0; i < 4; ++i) {
        v[i] = reinterpret_cast<const float4*>(xr)[i * 256 + t];
        sum += v[i].x + v[i].y + v[i].z + v[i].w;
        sumsq += v[i].x * v[i].x + v[i].y * v[i].y + v[i].z * v[i].z + v[i].w * v[i].w;
    }
#pragma unroll
    for (int off = 32; off > 0; off >>= 1) {
        sum += __shfl_down(sum, off);
        sumsq += __shfl_down(sumsq, off);
    }
    __shared__ float s_sum[4], s_sq[4];
    const int lane = t & 63, w = t >> 6;
    if (lane == 0) { s_sum[w] = sum; s_sq[w] = sumsq; }
    __syncthreads();
    sum = s_sum[0] + s_sum[1] + s_sum[2] + s_sum[3];
    sumsq = s_sq[0] + s_sq[1] + s_sq[2] + s_sq[3];

    const float mu = sum * (1.0f / K_DIM);
    const float var = sumsq * (1.0f / K_DIM) - mu * mu;
    const float rstd = rsqrtf(var + LN_EPSf);
    const float qs = QBf / gamma_p[0];
    const float lo = -QBf + EPf, hi = QBf - EPf;

    _Float16* xqr = xq + (size_t)row * K_DIM;
#pragma unroll
    for (int i = 0; i < 4; ++i) {
        const int idx = i * 256 + t;
        const float4 g = reinterpret_cast<const float4*>(ln_g)[idx];
        const float4 b = reinterpret_cast<const float4*>(ln_b)[idx];
        const float q0 = fminf(fmaxf(((v[i].x - mu) * rstd * g.x + b.x) * qs, lo), hi);
        const float q1 = fminf(fmaxf(((v[i].y - mu) * rstd * g.y + b.y) * qs, lo), hi);
        const float q2 = fminf(fmaxf(((v[i].z - mu) * rstd * g.z + b.z) * qs, lo), hi);
        const float q3 = fminf(fmaxf(((v[i].w - mu) * rstd * g.w + b.w) * qs, lo), hi);
        alignas(8) _Float16 h[4] = {(_Float16)q0, (_Float16)q1, (_Float16)q2, (_Float16)q3};
        *reinterpret_cast<uint2*>(xqr + (size_t)idx * 4) = *reinterpret_cast<const uint2*>(h);
    }
}

// ---------------------------------------------------------------------------
// Kernel 2: w (fp32, K x N, values ±1) -> wt (fp16, N x K).  64x64 LDS tiles.
// ---------------------------------------------------------------------------
__global__ __launch_bounds__(256) void wtrans_kernel(
    const float* __restrict__ w, _Float16* __restrict__ wt)
{
    __shared__ _Float16 tile[64][72];
    const int t = threadIdx.x;
    const int bk = blockIdx.y * 64;   // k tile base
    const int bn = blockIdx.x * 64;   // n tile base
#pragma unroll
    for (int i = 0; i < 4; ++i) {
        const int li = i * 1024 + t * 4;
        const int r = li >> 6, c = li & 63;
        const float4 vv = *reinterpret_cast<const float4*>(
            w + (size_t)(bk + r) * N_DIM + bn + c);
        tile[r][c]     = (_Float16)vv.x;
        tile[r][c + 1] = (_Float16)vv.y;
        tile[r][c + 2] = (_Float16)vv.z;
        tile[r][c + 3] = (_Float16)vv.w;
    }
    __syncthreads();
#pragma unroll
    for (int i = 0; i < 4; ++i) {
        const int li = i * 1024 + t * 4;
        const int r = li >> 6, c = li & 63;   // r = n-in-tile, c = k-in-tile
        alignas(8) _Float16 h[4] = {tile[c][r], tile[c + 1][r], tile[c + 2][r], tile[c + 3][r]};
        *reinterpret_cast<uint2*>(wt + (size_t)(bn + r) * K_DIM + bk + c) =
            *reinterpret_cast<const uint2*>(h);
    }
}

// ---------------------------------------------------------------------------
// Kernel 3: GEMM  C[M,N] = A[M,K] * Bt[N,K]^T  * scale  (fp16 MFMA, fp32 acc)
// 128x128 tile, BK=64, 4 waves, each wave 64x64 (4x4 of 16x16x32 fragments).
// T2 both-sides XOR swizzle: LDS stays linear (global_load_lds requirement);
// the 16B chunk j within row m holds global chunk (j ^ (m&7)); reads apply
// the same XOR.  Makes every ds_read_b128 bank-conflict-free.
// ---------------------------------------------------------------------------
__global__ __launch_bounds__(256) void gemm_kernel(
    const _Float16* __restrict__ A,
    const _Float16* __restrict__ Bt,
    float* __restrict__ C,
    const float* __restrict__ beta_p,
    const float* __restrict__ gamma_p)
{
    constexpr int BK = 64;              // halfs; row = 8 chunks of 16B
    __shared__ _Float16 As[128 * BK];   // physical-linear, 16 KiB
    __shared__ _Float16 Bs[128 * BK];

    const int t = threadIdx.x;
    const int bm = blockIdx.y * 128;
    const int bn = blockIdx.x * 128;
    const int lane = t & 63;
    const int w = t >> 6;
    const int wr = (w >> 1) * 64;       // wave row offset in tile
    const int wc = (w & 1) * 64;        // wave col offset in tile
    const int fr = lane & 15;           // fragment row/col within 16
    // read-side swizzle: chunk j for row r lives at physical chunk j^(r&7).
    // r&7 == fr&7 (row = wr + m*16 + fr, wr%64==0, m*16%8==0).
    // j = kk*4 + (lane>>4)  ->  phys = ((lane>>4) ^ (fr&7)) ^ (kk*4)
    const int jswz0 = (((lane >> 4) ^ (fr & 7)) << 3);   // halfs, kk=0
    // kk=1 offset: jswz0 ^ 32

    f32x4 acc[4][4];
#pragma unroll
    for (int m = 0; m < 4; ++m)
#pragma unroll
        for (int n = 0; n < 4; ++n)
            acc[m][n] = (f32x4){0.f, 0.f, 0.f, 0.f};

    const _Float16* Abase = A + (size_t)bm * K_DIM;
    const _Float16* Bbase = Bt + (size_t)bn * K_DIM;

    for (int k0 = 0; k0 < K_DIM; k0 += BK) {
        // ---- stage A,B tiles: 1024 16B chunks each; LDS dest linear,
        //      global source pre-swizzled (rule #21: both-sides-or-neither)
#pragma unroll
        for (int i = 0; i < 4; ++i) {
            const int c = i * 256 + t;
            const int m = c >> 3;                         // row within tile
            const int kc = (((c & 7) ^ (m & 7)) << 3);    // swizzled k offset (halfs)
            GLOAD_LDS16(Abase + (size_t)m * K_DIM + k0 + kc, As + c * 8);
            GLOAD_LDS16(Bbase + (size_t)m * K_DIM + k0 + kc, Bs + c * 8);
        }
        __syncthreads();   // compiler drains vmcnt before s_barrier

        // ---- compute: 2 K=32 slices, 16 MFMAs each ----
#pragma unroll
        for (int kk = 0; kk < 2; ++kk) {
            const int ks = jswz0 ^ (kk << 5);
            f16x8 a_frag[4], b_frag[4];
#pragma unroll
            for (int m = 0; m < 4; ++m)
                a_frag[m] = *reinterpret_cast<const f16x8*>(As + (wr + m * 16 + fr) * BK + ks);
#pragma unroll
            for (int n = 0; n < 4; ++n)
                b_frag[n] = *reinterpret_cast<const f16x8*>(Bs + (wc + n * 16 + fr) * BK + ks);
#pragma unroll
            for (int m = 0; m < 4; ++m)
#pragma unroll
                for (int n = 0; n < 4; ++n)
                    acc[m][n] = __builtin_amdgcn_mfma_f32_16x16x32_f16(
                        a_frag[m], b_frag[n], acc[m][n], 0, 0, 0);
        }
        __syncthreads();
    }

    // ---- epilogue: scale + store.  C/D layout: col=lane&15, row=(lane>>4)*4+j
    const float scale = beta_p[0] * gamma_p[0] * (1.0f / QBf);
    const int ocol = bn + wc + fr;
    const int orow = bm + wr + (lane >> 4) * 4;
#pragma unroll
    for (int m = 0; m < 4; ++m) {
#pragma unroll
        for (int j = 0; j < 4; ++j) {
            float* crow = C + (size_t)(orow + m * 16 + j) * N_DIM + ocol;
#pragma unroll
            for (int n = 0; n < 4; ++n)
                crow[n * 16] = acc[m][n][j] * scale;
        }
    }
}

// ---------------------------------------------------------------------------
extern "C" void kernel_launch(void* const* d_in, const int* in_sizes, int n_in,
                              void* d_out, int out_size, void* d_ws, size_t ws_size,
                              hipStream_t stream)
{
    const float* x       = (const float*)d_in[0];
    const float* w       = (const float*)d_in[1];
    const float* ln_g    = (const float*)d_in[2];
    const float* ln_b    = (const float*)d_in[3];
    const float* beta_p  = (const float*)d_in[4];
    const float* gamma_p = (const float*)d_in[5];
    float* out = (float*)d_out;

    const int M = in_sizes[0] / K_DIM;   // 8192

    _Float16* xq = (_Float16*)d_ws;
    _Float16* wt = (_Float16*)((char*)d_ws + (size_t)M * K_DIM * sizeof(_Float16));

    ln_quant_kernel<<<M, 256, 0, stream>>>(x, ln_g, ln_b, gamma_p, xq);
    wtrans_kernel<<<dim3(N_DIM / 64, K_DIM / 64), 256, 0, stream>>>(w, wt);
    gemm_kernel<<<dim3(N_DIM / 128, M / 128), 256, 0, stream>>>(xq, wt, out, beta_p, gamma_p);
}

// Round 3
// 288.471 us; speedup vs baseline: 1.4656x; 1.2469x over previous
//
#include <hip/hip_runtime.h>
#include <hip/hip_fp16.h>

using f32x4 = __attribute__((ext_vector_type(4))) float;
using f16x8 = __attribute__((ext_vector_type(8))) _Float16;

constexpr int K_DIM = 4096;   // N_IN
constexpr int N_DIM = 4096;   // N_OUT
constexpr float QBf = 128.0f;
constexpr float EPf = 0.01f;
constexpr float LN_EPSf = 1e-5f;

#define GLOAD_LDS16(gp, lp)                                                  \
    __builtin_amdgcn_global_load_lds(                                        \
        (const __attribute__((address_space(1))) void*)(gp),                 \
        (__attribute__((address_space(3))) void*)(lp), 16, 0, 0)

#define BARRIER()                                                            \
    do { asm volatile("" ::: "memory");                                      \
         __builtin_amdgcn_s_barrier();                                       \
         asm volatile("" ::: "memory"); } while (0)

// ---------------------------------------------------------------------------
// Kernel 1: fused LayerNorm + ABSMax-quant + fp16 cast.  One block per row.
// ---------------------------------------------------------------------------
__global__ __launch_bounds__(256) void ln_quant_kernel(
    const float* __restrict__ x,
    const float* __restrict__ ln_g,
    const float* __restrict__ ln_b,
    const float* __restrict__ gamma_p,
    _Float16* __restrict__ xq)
{
    const int row = blockIdx.x;
    const int t = threadIdx.x;
    const float* xr = x + (size_t)row * K_DIM;

    float4 v[4];
    float sum = 0.f, sumsq = 0.f;
#pragma unroll
    for (int i = 0; i < 4; ++i) {
        v[i] = reinterpret_cast<const float4*>(xr)[i * 256 + t];
        sum += v[i].x + v[i].y + v[i].z + v[i].w;
        sumsq += v[i].x * v[i].x + v[i].y * v[i].y + v[i].z * v[i].z + v[i].w * v[i].w;
    }
#pragma unroll
    for (int off = 32; off > 0; off >>= 1) {
        sum += __shfl_down(sum, off);
        sumsq += __shfl_down(sumsq, off);
    }
    __shared__ float s_sum[4], s_sq[4];
    const int lane = t & 63, w = t >> 6;
    if (lane == 0) { s_sum[w] = sum; s_sq[w] = sumsq; }
    __syncthreads();
    sum = s_sum[0] + s_sum[1] + s_sum[2] + s_sum[3];
    sumsq = s_sq[0] + s_sq[1] + s_sq[2] + s_sq[3];

    const float mu = sum * (1.0f / K_DIM);
    const float var = sumsq * (1.0f / K_DIM) - mu * mu;
    const float rstd = rsqrtf(var + LN_EPSf);
    const float qs = QBf / gamma_p[0];
    const float lo = -QBf + EPf, hi = QBf - EPf;

    _Float16* xqr = xq + (size_t)row * K_DIM;
#pragma unroll
    for (int i = 0; i < 4; ++i) {
        const int idx = i * 256 + t;
        const float4 g = reinterpret_cast<const float4*>(ln_g)[idx];
        const float4 b = reinterpret_cast<const float4*>(ln_b)[idx];
        const float q0 = fminf(fmaxf(((v[i].x - mu) * rstd * g.x + b.x) * qs, lo), hi);
        const float q1 = fminf(fmaxf(((v[i].y - mu) * rstd * g.y + b.y) * qs, lo), hi);
        const float q2 = fminf(fmaxf(((v[i].z - mu) * rstd * g.z + b.z) * qs, lo), hi);
        const float q3 = fminf(fmaxf(((v[i].w - mu) * rstd * g.w + b.w) * qs, lo), hi);
        alignas(8) _Float16 h[4] = {(_Float16)q0, (_Float16)q1, (_Float16)q2, (_Float16)q3};
        *reinterpret_cast<uint2*>(xqr + (size_t)idx * 4) = *reinterpret_cast<const uint2*>(h);
    }
}

// ---------------------------------------------------------------------------
// Kernel 2: w (fp32, K x N, values ±1) -> wt (fp16, N x K).  64x64 LDS tiles.
// ---------------------------------------------------------------------------
__global__ __launch_bounds__(256) void wtrans_kernel(
    const float* __restrict__ w, _Float16* __restrict__ wt)
{
    __shared__ _Float16 tile[64][72];
    const int t = threadIdx.x;
    const int bk = blockIdx.y * 64;
    const int bn = blockIdx.x * 64;
#pragma unroll
    for (int i = 0; i < 4; ++i) {
        const int li = i * 1024 + t * 4;
        const int r = li >> 6, c = li & 63;
        const float4 vv = *reinterpret_cast<const float4*>(
            w + (size_t)(bk + r) * N_DIM + bn + c);
        tile[r][c]     = (_Float16)vv.x;
        tile[r][c + 1] = (_Float16)vv.y;
        tile[r][c + 2] = (_Float16)vv.z;
        tile[r][c + 3] = (_Float16)vv.w;
    }
    __syncthreads();
#pragma unroll
    for (int i = 0; i < 4; ++i) {
        const int li = i * 1024 + t * 4;
        const int r = li >> 6, c = li & 63;
        alignas(8) _Float16 h[4] = {tile[c][r], tile[c + 1][r], tile[c + 2][r], tile[c + 3][r]};
        *reinterpret_cast<uint2*>(wt + (size_t)(bn + r) * K_DIM + bk + c) =
            *reinterpret_cast<const uint2*>(h);
    }
}

// ---------------------------------------------------------------------------
// Kernel 3: GEMM  C[M,N] = A[M,K] * Bt[N,K]^T * scale   (fp16 MFMA, fp32 acc)
// 256x256 tile, BK=64, 512 threads = 8 waves (2M x 4N), wave tile 128x64.
// 8-phase schedule (T3+T5): per phase {ds_read frag subtile, stage 1
// half-tile via global_load_lds} -> s_barrier -> lgkmcnt(0) -> setprio(1) ->
// 16 MFMA -> setprio(0) -> [vmcnt(0) at q==3] -> s_barrier.
// Phases 0-3 compute tile kt (buf0) and stage tile kt+1 -> buf1;
// phases 4-7 compute tile kt+1 (buf1) and stage tile kt+2 -> buf0.
// T2 XOR swizzle (chunk j of row r at physical j^(r&7)) on both stage-source
// and read side; LDS dest stays linear (global_load_lds requirement).
// ---------------------------------------------------------------------------
__global__ __launch_bounds__(512, 2) void gemm_kernel(
    const _Float16* __restrict__ A,
    const _Float16* __restrict__ Bt,
    float* __restrict__ C,
    const float* __restrict__ beta_p,
    const float* __restrict__ gamma_p)
{
    constexpr int NT = K_DIM / 64;                 // 64 K-tiles
    __shared__ _Float16 lds[65536];                // 128 KiB: [buf][A|B][256][64]

    const int t = threadIdx.x;
    const int bm = blockIdx.y * 256;
    const int bn = blockIdx.x * 256;
    const int lane = t & 63;
    const int w = t >> 6;
    const int wm = w >> 2;            // 0..1
    const int wn = w & 3;             // 0..3
    const int fr = lane & 15;
    const int lg = lane >> 4;         // 0..3
    const int swz = ((lg ^ (fr & 7)) << 3);   // halfs; kk=1 -> swz ^ 32

    const _Float16* Abase = A + (size_t)bm * K_DIM;
    const _Float16* Bbase = Bt + (size_t)bn * K_DIM;

    // stage half-tile ht (0=Ah0,1=Ah1,2=Bh0,3=Bh1) of K-tile kt into buffer b
#define STAGE_HT(b, ht, kt)                                                   \
    do {                                                                      \
        const _Float16* gbase = ((ht) < 2) ? Abase : Bbase;                   \
        _Float16* lbase = lds + (b) * 32768 + (((ht) < 2) ? 0 : 16384)        \
                          + ((ht) & 1) * 8192;                                \
        _Pragma("unroll")                                                     \
        for (int rnd = 0; rnd < 2; ++rnd) {                                   \
            const int c = rnd * 512 + t;                                      \
            const int r = c >> 3, j = c & 7;                                  \
            GLOAD_LDS16(gbase + (size_t)(((ht) & 1) * 128 + r) * K_DIM        \
                            + (kt) * 64 + ((j ^ (r & 7)) << 3),               \
                        lbase + c * 8);                                       \
        }                                                                     \
    } while (0)

    f32x4 acc[8][4];
#pragma unroll
    for (int m = 0; m < 8; ++m)
#pragma unroll
        for (int n = 0; n < 4; ++n)
            acc[m][n] = (f32x4){0.f, 0.f, 0.f, 0.f};

    // prologue: stage K-tile 0 into buf0, drain, sync
    STAGE_HT(0, 0, 0); STAGE_HT(0, 1, 0); STAGE_HT(0, 2, 0); STAGE_HT(0, 3, 0);
    asm volatile("s_waitcnt vmcnt(0)" ::: "memory");
    BARRIER();

    f16x8 bfrag[4][2];

    for (int kt = 0; kt < NT; kt += 2) {
#pragma unroll
        for (int h = 0; h < 2; ++h) {
            const int stile = kt + 1 + h;                 // stage target tile
            const _Float16* abuf = lds + h * 32768 + (wm * 128) * 64;
            const _Float16* bbuf = lds + h * 32768 + 16384 + (wn * 64) * 64;
#pragma unroll
            for (int q = 0; q < 4; ++q) {
                // ---- ds_read fragment subtile (B: 8 reads at q==0 only;
                //      A: 4 reads per phase) ----
                if (q == 0) {
#pragma unroll
                    for (int n = 0; n < 4; ++n)
#pragma unroll
                        for (int kk = 0; kk < 2; ++kk)
                            bfrag[n][kk] = *reinterpret_cast<const f16x8*>(
                                bbuf + (n * 16 + fr) * 64 + (swz ^ (kk << 5)));
                }
                f16x8 afrag[2][2];
#pragma unroll
                for (int m2 = 0; m2 < 2; ++m2)
#pragma unroll
                    for (int kk = 0; kk < 2; ++kk)
                        afrag[m2][kk] = *reinterpret_cast<const f16x8*>(
                            abuf + (q * 32 + m2 * 16 + fr) * 64 + (swz ^ (kk << 5)));

                // ---- issue 1 half-tile prefetch (2 x global_load_lds) ----
                if (stile < NT) {
                    if (q == 0) STAGE_HT(h ^ 1, 0, stile);
                    if (q == 1) STAGE_HT(h ^ 1, 1, stile);
                    if (q == 2) STAGE_HT(h ^ 1, 2, stile);
                    if (q == 3) STAGE_HT(h ^ 1, 3, stile);
                }

                BARRIER();
                asm volatile("s_waitcnt lgkmcnt(0)" ::: "memory");
                __builtin_amdgcn_sched_barrier(0);
                __builtin_amdgcn_s_setprio(1);
#pragma unroll
                for (int m2 = 0; m2 < 2; ++m2)
#pragma unroll
                    for (int n = 0; n < 4; ++n)
#pragma unroll
                        for (int kk = 0; kk < 2; ++kk)
                            acc[q * 2 + m2][n] = __builtin_amdgcn_mfma_f32_16x16x32_f16(
                                afrag[m2][kk], bfrag[n][kk], acc[q * 2 + m2][n], 0, 0, 0);
                __builtin_amdgcn_s_setprio(0);
                if (q == 3)   // tile (kt+h+1) fully staged & drained before use
                    asm volatile("s_waitcnt vmcnt(0)" ::: "memory");
                BARRIER();
            }
        }
    }

    // ---- epilogue: C/D layout col=lane&15, row=(lane>>4)*4+j ----
    const float scale = beta_p[0] * gamma_p[0] * (1.0f / QBf);
    const int orow = bm + wm * 128 + lg * 4;
    const int ocol = bn + wn * 64 + fr;
#pragma unroll
    for (int m = 0; m < 8; ++m) {
#pragma unroll
        for (int j = 0; j < 4; ++j) {
            float* crow = C + (size_t)(orow + m * 16 + j) * N_DIM + ocol;
#pragma unroll
            for (int n = 0; n < 4; ++n)
                crow[n * 16] = acc[m][n][j] * scale;
        }
    }
#undef STAGE_HT
}

// ---------------------------------------------------------------------------
extern "C" void kernel_launch(void* const* d_in, const int* in_sizes, int n_in,
                              void* d_out, int out_size, void* d_ws, size_t ws_size,
                              hipStream_t stream)
{
    const float* x       = (const float*)d_in[0];
    const float* w       = (const float*)d_in[1];
    const float* ln_g    = (const float*)d_in[2];
    const float* ln_b    = (const float*)d_in[3];
    const float* beta_p  = (const float*)d_in[4];
    const float* gamma_p = (const float*)d_in[5];
    float* out = (float*)d_out;

    const int M = in_sizes[0] / K_DIM;   // 8192

    _Float16* xq = (_Float16*)d_ws;
    _Float16* wt = (_Float16*)((char*)d_ws + (size_t)M * K_DIM * sizeof(_Float16));

    ln_quant_kernel<<<M, 256, 0, stream>>>(x, ln_g, ln_b, gamma_p, xq);
    wtrans_kernel<<<dim3(N_DIM / 64, K_DIM / 64), 256, 0, stream>>>(w, wt);
    gemm_kernel<<<dim3(N_DIM / 256, M / 256), 512, 0, stream>>>(xq, wt, out, beta_p, gamma_p);
}

// Round 4
// 280.535 us; speedup vs baseline: 1.5071x; 1.0283x over previous
//
#include <hip/hip_runtime.h>
#include <hip/hip_fp16.h>

using f32x4 = __attribute__((ext_vector_type(4))) float;
using f16x8 = __attribute__((ext_vector_type(8))) _Float16;

constexpr int K_DIM = 4096;   // N_IN
constexpr int N_DIM = 4096;   // N_OUT
constexpr float QBf = 128.0f;
constexpr float EPf = 0.01f;
constexpr float LN_EPSf = 1e-5f;

#define GLOAD_LDS16(gp, lp)                                                  \
    __builtin_amdgcn_global_load_lds(                                        \
        (const __attribute__((address_space(1))) void*)(gp),                 \
        (__attribute__((address_space(3))) void*)(lp), 16, 0, 0)

#define BARRIER()                                                            \
    do { asm volatile("" ::: "memory");                                      \
         __builtin_amdgcn_s_barrier();                                       \
         asm volatile("" ::: "memory"); } while (0)

// ---------------------------------------------------------------------------
// Kernel 1: fused LayerNorm + ABSMax-quant + fp16 cast.  One block per row.
// ---------------------------------------------------------------------------
__global__ __launch_bounds__(256) void ln_quant_kernel(
    const float* __restrict__ x,
    const float* __restrict__ ln_g,
    const float* __restrict__ ln_b,
    const float* __restrict__ gamma_p,
    _Float16* __restrict__ xq)
{
    const int row = blockIdx.x;
    const int t = threadIdx.x;
    const float* xr = x + (size_t)row * K_DIM;

    float4 v[4];
    float sum = 0.f, sumsq = 0.f;
#pragma unroll
    for (int i = 0; i < 4; ++i) {
        v[i] = reinterpret_cast<const float4*>(xr)[i * 256 + t];
        sum += v[i].x + v[i].y + v[i].z + v[i].w;
        sumsq += v[i].x * v[i].x + v[i].y * v[i].y + v[i].z * v[i].z + v[i].w * v[i].w;
    }
#pragma unroll
    for (int off = 32; off > 0; off >>= 1) {
        sum += __shfl_down(sum, off);
        sumsq += __shfl_down(sumsq, off);
    }
    __shared__ float s_sum[4], s_sq[4];
    const int lane = t & 63, w = t >> 6;
    if (lane == 0) { s_sum[w] = sum; s_sq[w] = sumsq; }
    __syncthreads();
    sum = s_sum[0] + s_sum[1] + s_sum[2] + s_sum[3];
    sumsq = s_sq[0] + s_sq[1] + s_sq[2] + s_sq[3];

    const float mu = sum * (1.0f / K_DIM);
    const float var = sumsq * (1.0f / K_DIM) - mu * mu;
    const float rstd = rsqrtf(var + LN_EPSf);
    const float qs = QBf / gamma_p[0];
    const float lo = -QBf + EPf, hi = QBf - EPf;

    _Float16* xqr = xq + (size_t)row * K_DIM;
#pragma unroll
    for (int i = 0; i < 4; ++i) {
        const int idx = i * 256 + t;
        const float4 g = reinterpret_cast<const float4*>(ln_g)[idx];
        const float4 b = reinterpret_cast<const float4*>(ln_b)[idx];
        const float q0 = fminf(fmaxf(((v[i].x - mu) * rstd * g.x + b.x) * qs, lo), hi);
        const float q1 = fminf(fmaxf(((v[i].y - mu) * rstd * g.y + b.y) * qs, lo), hi);
        const float q2 = fminf(fmaxf(((v[i].z - mu) * rstd * g.z + b.z) * qs, lo), hi);
        const float q3 = fminf(fmaxf(((v[i].w - mu) * rstd * g.w + b.w) * qs, lo), hi);
        alignas(8) _Float16 h[4] = {(_Float16)q0, (_Float16)q1, (_Float16)q2, (_Float16)q3};
        *reinterpret_cast<uint2*>(xqr + (size_t)idx * 4) = *reinterpret_cast<const uint2*>(h);
    }
}

// ---------------------------------------------------------------------------
// Kernel 2: w (fp32, K x N, values ±1) -> wt (fp16, N x K).  64x64 LDS tiles.
// ---------------------------------------------------------------------------
__global__ __launch_bounds__(256) void wtrans_kernel(
    const float* __restrict__ w, _Float16* __restrict__ wt)
{
    __shared__ _Float16 tile[64][72];
    const int t = threadIdx.x;
    const int bk = blockIdx.y * 64;
    const int bn = blockIdx.x * 64;
#pragma unroll
    for (int i = 0; i < 4; ++i) {
        const int li = i * 1024 + t * 4;
        const int r = li >> 6, c = li & 63;
        const float4 vv = *reinterpret_cast<const float4*>(
            w + (size_t)(bk + r) * N_DIM + bn + c);
        tile[r][c]     = (_Float16)vv.x;
        tile[r][c + 1] = (_Float16)vv.y;
        tile[r][c + 2] = (_Float16)vv.z;
        tile[r][c + 3] = (_Float16)vv.w;
    }
    __syncthreads();
#pragma unroll
    for (int i = 0; i < 4; ++i) {
        const int li = i * 1024 + t * 4;
        const int r = li >> 6, c = li & 63;
        alignas(8) _Float16 h[4] = {tile[c][r], tile[c + 1][r], tile[c + 2][r], tile[c + 3][r]};
        *reinterpret_cast<uint2*>(wt + (size_t)(bn + r) * K_DIM + bk + c) =
            *reinterpret_cast<const uint2*>(h);
    }
}

// ---------------------------------------------------------------------------
// Kernel 3: GEMM  C[M,N] = A[M,K] * Bt[N,K]^T * scale   (fp16 MFMA, fp32 acc)
// 256x256 tile, BK=64, 512 threads = 8 waves (2M x 4N), wave tile 128x64.
// 8-phase schedule (T3+T5) with stage-early prefetch: all 4 half-tiles of
// the next K-tile are issued at phases q0/q1, giving the last-issued loads
// ~2.5 MFMA-phases of cover before the single vmcnt(0) drain at q3.
// T1: XCD-aware bijective block swizzle (each XCD owns an 8x8 block square).
// T2: XOR swizzle (chunk j of row r at physical j^(r&7)) on stage-source and
// read side; LDS dest stays linear (global_load_lds requirement).
// ---------------------------------------------------------------------------
__global__ __launch_bounds__(512, 2) void gemm_kernel(
    const _Float16* __restrict__ A,
    const _Float16* __restrict__ Bt,
    float* __restrict__ C,
    const float* __restrict__ beta_p,
    const float* __restrict__ gamma_p)
{
    constexpr int NT = K_DIM / 64;                 // 64 K-tiles
    __shared__ _Float16 lds[65536];                // 128 KiB: [buf][A|B][256][64]

    const int t = threadIdx.x;
    // ---- XCD swizzle: flat id -> 8x8 square per XCD (512 blocks, 16x32 grid)
    const int flat = blockIdx.y * gridDim.x + blockIdx.x;
    const int xcd = flat & 7;
    const int r8 = flat >> 3;                       // 0..63
    const int by = ((xcd >> 1) << 3) + (r8 >> 3);   // 0..31  (M index)
    const int bx = ((xcd & 1) << 3) + (r8 & 7);     // 0..15  (N index)
    const int bm = by * 256;
    const int bn = bx * 256;

    const int lane = t & 63;
    const int w = t >> 6;
    const int wm = w >> 2;            // 0..1
    const int wn = w & 3;             // 0..3
    const int fr = lane & 15;
    const int lg = lane >> 4;         // 0..3
    const int swz = ((lg ^ (fr & 7)) << 3);   // halfs; kk=1 -> swz ^ 32

    const _Float16* Abase = A + (size_t)bm * K_DIM;
    const _Float16* Bbase = Bt + (size_t)bn * K_DIM;

    // stage half-tile ht (0=Ah0,1=Ah1,2=Bh0,3=Bh1) of K-tile kt into buffer b
#define STAGE_HT(b, ht, kt)                                                   \
    do {                                                                      \
        const _Float16* gbase = ((ht) < 2) ? Abase : Bbase;                   \
        _Float16* lbase = lds + (b) * 32768 + (((ht) < 2) ? 0 : 16384)        \
                          + ((ht) & 1) * 8192;                                \
        _Pragma("unroll")                                                     \
        for (int rnd = 0; rnd < 2; ++rnd) {                                   \
            const int c = rnd * 512 + t;                                      \
            const int r = c >> 3, j = c & 7;                                  \
            GLOAD_LDS16(gbase + (size_t)(((ht) & 1) * 128 + r) * K_DIM        \
                            + (kt) * 64 + ((j ^ (r & 7)) << 3),               \
                        lbase + c * 8);                                       \
        }                                                                     \
    } while (0)

    f32x4 acc[8][4];
#pragma unroll
    for (int m = 0; m < 8; ++m)
#pragma unroll
        for (int n = 0; n < 4; ++n)
            acc[m][n] = (f32x4){0.f, 0.f, 0.f, 0.f};

    // prologue: stage K-tile 0 into buf0, drain, sync
    STAGE_HT(0, 0, 0); STAGE_HT(0, 1, 0); STAGE_HT(0, 2, 0); STAGE_HT(0, 3, 0);
    asm volatile("s_waitcnt vmcnt(0)" ::: "memory");
    BARRIER();

    f16x8 bfrag[4][2];

    for (int kt = 0; kt < NT; kt += 2) {
#pragma unroll
        for (int h = 0; h < 2; ++h) {
            const int stile = kt + 1 + h;                 // stage target tile
            const _Float16* abuf = lds + h * 32768 + (wm * 128) * 64;
            const _Float16* bbuf = lds + h * 32768 + 16384 + (wn * 64) * 64;
#pragma unroll
            for (int q = 0; q < 4; ++q) {
                // ---- ds_read fragment subtile (B: 8 reads at q==0 only;
                //      A: 4 reads per phase) ----
                if (q == 0) {
#pragma unroll
                    for (int n = 0; n < 4; ++n)
#pragma unroll
                        for (int kk = 0; kk < 2; ++kk)
                            bfrag[n][kk] = *reinterpret_cast<const f16x8*>(
                                bbuf + (n * 16 + fr) * 64 + (swz ^ (kk << 5)));
                }
                f16x8 afrag[2][2];
#pragma unroll
                for (int m2 = 0; m2 < 2; ++m2)
#pragma unroll
                    for (int kk = 0; kk < 2; ++kk)
                        afrag[m2][kk] = *reinterpret_cast<const f16x8*>(
                            abuf + (q * 32 + m2 * 16 + fr) * 64 + (swz ^ (kk << 5)));

                // ---- stage-early: 2 half-tiles at q0, 2 at q1 ----
                if (stile < NT) {
                    if (q == 0) { STAGE_HT(h ^ 1, 0, stile); STAGE_HT(h ^ 1, 1, stile); }
                    if (q == 1) { STAGE_HT(h ^ 1, 2, stile); STAGE_HT(h ^ 1, 3, stile); }
                }

                BARRIER();
                asm volatile("s_waitcnt lgkmcnt(0)" ::: "memory");
                __builtin_amdgcn_sched_barrier(0);
                __builtin_amdgcn_s_setprio(1);
#pragma unroll
                for (int m2 = 0; m2 < 2; ++m2)
#pragma unroll
                    for (int n = 0; n < 4; ++n)
#pragma unroll
                        for (int kk = 0; kk < 2; ++kk)
                            acc[q * 2 + m2][n] = __builtin_amdgcn_mfma_f32_16x16x32_f16(
                                afrag[m2][kk], bfrag[n][kk], acc[q * 2 + m2][n], 0, 0, 0);
                __builtin_amdgcn_s_setprio(0);
                if (q == 3)   // tile (kt+h+1) fully staged & drained before use
                    asm volatile("s_waitcnt vmcnt(0)" ::: "memory");
                BARRIER();
            }
        }
    }

    // ---- epilogue: C/D layout col=lane&15, row=(lane>>4)*4+j ----
    const float scale = beta_p[0] * gamma_p[0] * (1.0f / QBf);
    const int orow = bm + wm * 128 + lg * 4;
    const int ocol = bn + wn * 64 + fr;
#pragma unroll
    for (int m = 0; m < 8; ++m) {
#pragma unroll
        for (int j = 0; j < 4; ++j) {
            float* crow = C + (size_t)(orow + m * 16 + j) * N_DIM + ocol;
#pragma unroll
            for (int n = 0; n < 4; ++n)
                crow[n * 16] = acc[m][n][j] * scale;
        }
    }
#undef STAGE_HT
}

// ---------------------------------------------------------------------------
extern "C" void kernel_launch(void* const* d_in, const int* in_sizes, int n_in,
                              void* d_out, int out_size, void* d_ws, size_t ws_size,
                              hipStream_t stream)
{
    const float* x       = (const float*)d_in[0];
    const float* w       = (const float*)d_in[1];
    const float* ln_g    = (const float*)d_in[2];
    const float* ln_b    = (const float*)d_in[3];
    const float* beta_p  = (const float*)d_in[4];
    const float* gamma_p = (const float*)d_in[5];
    float* out = (float*)d_out;

    const int M = in_sizes[0] / K_DIM;   // 8192

    _Float16* xq = (_Float16*)d_ws;
    _Float16* wt = (_Float16*)((char*)d_ws + (size_t)M * K_DIM * sizeof(_Float16));

    ln_quant_kernel<<<M, 256, 0, stream>>>(x, ln_g, ln_b, gamma_p, xq);
    wtrans_kernel<<<dim3(N_DIM / 64, K_DIM / 64), 256, 0, stream>>>(w, wt);
    gemm_kernel<<<dim3(N_DIM / 256, M / 256), 512, 0, stream>>>(xq, wt, out, beta_p, gamma_p);
}

// Round 5
// 271.407 us; speedup vs baseline: 1.5578x; 1.0336x over previous
//
#include <hip/hip_runtime.h>
#include <hip/hip_fp16.h>

using f32x4 = __attribute__((ext_vector_type(4))) float;
using f16x8 = __attribute__((ext_vector_type(8))) _Float16;

constexpr int K_DIM = 4096;   // N_IN
constexpr int N_DIM = 4096;   // N_OUT
constexpr float QBf = 128.0f;
constexpr float EPf = 0.01f;
constexpr float LN_EPSf = 1e-5f;

#define GLOAD_LDS16(gp, lp)                                                  \
    __builtin_amdgcn_global_load_lds(                                        \
        (const __attribute__((address_space(1))) void*)(gp),                 \
        (__attribute__((address_space(3))) void*)(lp), 16, 0, 0)

#define BARRIER()                                                            \
    do { asm volatile("" ::: "memory");                                      \
         __builtin_amdgcn_s_barrier();                                       \
         asm volatile("" ::: "memory"); } while (0)

// ---------------------------------------------------------------------------
// Kernel 1: fused LayerNorm + ABSMax-quant + fp16 cast.  One block per row.
// ---------------------------------------------------------------------------
__global__ __launch_bounds__(256) void ln_quant_kernel(
    const float* __restrict__ x,
    const float* __restrict__ ln_g,
    const float* __restrict__ ln_b,
    const float* __restrict__ gamma_p,
    _Float16* __restrict__ xq)
{
    const int row = blockIdx.x;
    const int t = threadIdx.x;
    const float* xr = x + (size_t)row * K_DIM;

    float4 v[4];
    float sum = 0.f, sumsq = 0.f;
#pragma unroll
    for (int i = 0; i < 4; ++i) {
        v[i] = reinterpret_cast<const float4*>(xr)[i * 256 + t];
        sum += v[i].x + v[i].y + v[i].z + v[i].w;
        sumsq += v[i].x * v[i].x + v[i].y * v[i].y + v[i].z * v[i].z + v[i].w * v[i].w;
    }
#pragma unroll
    for (int off = 32; off > 0; off >>= 1) {
        sum += __shfl_down(sum, off);
        sumsq += __shfl_down(sumsq, off);
    }
    __shared__ float s_sum[4], s_sq[4];
    const int lane = t & 63, w = t >> 6;
    if (lane == 0) { s_sum[w] = sum; s_sq[w] = sumsq; }
    __syncthreads();
    sum = s_sum[0] + s_sum[1] + s_sum[2] + s_sum[3];
    sumsq = s_sq[0] + s_sq[1] + s_sq[2] + s_sq[3];

    const float mu = sum * (1.0f / K_DIM);
    const float var = sumsq * (1.0f / K_DIM) - mu * mu;
    const float rstd = rsqrtf(var + LN_EPSf);
    const float qs = QBf / gamma_p[0];
    const float lo = -QBf + EPf, hi = QBf - EPf;

    _Float16* xqr = xq + (size_t)row * K_DIM;
#pragma unroll
    for (int i = 0; i < 4; ++i) {
        const int idx = i * 256 + t;
        const float4 g = reinterpret_cast<const float4*>(ln_g)[idx];
        const float4 b = reinterpret_cast<const float4*>(ln_b)[idx];
        const float q0 = fminf(fmaxf(((v[i].x - mu) * rstd * g.x + b.x) * qs, lo), hi);
        const float q1 = fminf(fmaxf(((v[i].y - mu) * rstd * g.y + b.y) * qs, lo), hi);
        const float q2 = fminf(fmaxf(((v[i].z - mu) * rstd * g.z + b.z) * qs, lo), hi);
        const float q3 = fminf(fmaxf(((v[i].w - mu) * rstd * g.w + b.w) * qs, lo), hi);
        alignas(8) _Float16 h[4] = {(_Float16)q0, (_Float16)q1, (_Float16)q2, (_Float16)q3};
        *reinterpret_cast<uint2*>(xqr + (size_t)idx * 4) = *reinterpret_cast<const uint2*>(h);
    }
}

// ---------------------------------------------------------------------------
// Kernel 2: w (fp32, K x N, values ±1) -> wt (fp16, N x K).  64x64 LDS tiles.
// ---------------------------------------------------------------------------
__global__ __launch_bounds__(256) void wtrans_kernel(
    const float* __restrict__ w, _Float16* __restrict__ wt)
{
    __shared__ _Float16 tile[64][72];
    const int t = threadIdx.x;
    const int bk = blockIdx.y * 64;
    const int bn = blockIdx.x * 64;
#pragma unroll
    for (int i = 0; i < 4; ++i) {
        const int li = i * 1024 + t * 4;
        const int r = li >> 6, c = li & 63;
        const float4 vv = *reinterpret_cast<const float4*>(
            w + (size_t)(bk + r) * N_DIM + bn + c);
        tile[r][c]     = (_Float16)vv.x;
        tile[r][c + 1] = (_Float16)vv.y;
        tile[r][c + 2] = (_Float16)vv.z;
        tile[r][c + 3] = (_Float16)vv.w;
    }
    __syncthreads();
#pragma unroll
    for (int i = 0; i < 4; ++i) {
        const int li = i * 1024 + t * 4;
        const int r = li >> 6, c = li & 63;
        alignas(8) _Float16 h[4] = {tile[c][r], tile[c + 1][r], tile[c + 2][r], tile[c + 3][r]};
        *reinterpret_cast<uint2*>(wt + (size_t)(bn + r) * K_DIM + bk + c) =
            *reinterpret_cast<const uint2*>(h);
    }
}

// ---------------------------------------------------------------------------
// Kernel 3: GEMM  C[M,N] = A[M,K] * Bt[N,K]^T * scale   (fp16 MFMA, fp32 acc)
// 256x256 tile, BK=64, 512 threads = 8 waves (2M x 4N), wave tile 128x64.
// Pipelined 4-phase group per K-tile:
//   phase q: {issue A-frag ds_reads for q+1; issue ring stages;
//             lgkmcnt(4) [q's frags ready, q+1's in flight]; 16 MFMA; barrier}
// Counted-vmcnt ring (T4): stage A(t+1)->buf^1 at q0, B(t+2)->buf at q1/q2
// (B slots of tile t are free after q0: all waves' B reads complete before
// MFMA(q0) via lgkmcnt, barrier follows).  End-of-group vmcnt(4) leaves
// B(t+2) in flight - never drains to 0 in steady state.
// T1 XCD block swizzle; T2 XOR swizzle on stage-source and read side.
// ---------------------------------------------------------------------------
__global__ __launch_bounds__(512, 2) void gemm_kernel(
    const _Float16* __restrict__ A,
    const _Float16* __restrict__ Bt,
    float* __restrict__ C,
    const float* __restrict__ beta_p,
    const float* __restrict__ gamma_p)
{
    constexpr int NT = K_DIM / 64;                 // 64 K-tiles
    __shared__ _Float16 lds[65536];                // 128 KiB: [buf][A|B][256][64]

    const int t = threadIdx.x;
    // ---- XCD swizzle: flat id -> 8x8 square per XCD (512 blocks, 16x32 grid)
    const int flat = blockIdx.y * gridDim.x + blockIdx.x;
    const int xcd = flat & 7;
    const int r8 = flat >> 3;                       // 0..63
    const int by = ((xcd >> 1) << 3) + (r8 >> 3);   // 0..31  (M index)
    const int bx = ((xcd & 1) << 3) + (r8 & 7);     // 0..15  (N index)
    const int bm = by * 256;
    const int bn = bx * 256;

    const int lane = t & 63;
    const int w = t >> 6;
    const int wm = w >> 2;            // 0..1
    const int wn = w & 3;             // 0..3
    const int fr = lane & 15;
    const int lg = lane >> 4;         // 0..3
    const int swz = ((lg ^ (fr & 7)) << 3);   // halfs; kk=1 -> swz ^ 32

    const _Float16* Abase = A + (size_t)bm * K_DIM;
    const _Float16* Bbase = Bt + (size_t)bn * K_DIM;

    // stage half-tile ht (0=Ah0,1=Ah1,2=Bh0,3=Bh1) of K-tile kt into buffer b
#define STAGE_HT(b, ht, kt)                                                   \
    do {                                                                      \
        const _Float16* gbase = ((ht) < 2) ? Abase : Bbase;                   \
        _Float16* lbase = lds + (b) * 32768 + (((ht) < 2) ? 0 : 16384)        \
                          + ((ht) & 1) * 8192;                                \
        _Pragma("unroll")                                                     \
        for (int rnd = 0; rnd < 2; ++rnd) {                                   \
            const int c = rnd * 512 + t;                                      \
            const int r = c >> 3, j = c & 7;                                  \
            GLOAD_LDS16(gbase + (size_t)(((ht) & 1) * 128 + r) * K_DIM        \
                            + (kt) * 64 + ((j ^ (r & 7)) << 3),               \
                        lbase + c * 8);                                       \
        }                                                                     \
    } while (0)

    f32x4 acc[8][4];
#pragma unroll
    for (int m = 0; m < 8; ++m)
#pragma unroll
        for (int n = 0; n < 4; ++n)
            acc[m][n] = (f32x4){0.f, 0.f, 0.f, 0.f};

    // prologue: A(0),B(0) -> buf0; B(1) -> buf1; wait all but B(1); sync
    STAGE_HT(0, 0, 0); STAGE_HT(0, 1, 0); STAGE_HT(0, 2, 0); STAGE_HT(0, 3, 0);
    STAGE_HT(1, 2, 1); STAGE_HT(1, 3, 1);
    asm volatile("s_waitcnt vmcnt(4)" ::: "memory");
    BARRIER();

    for (int kt = 0; kt < NT; kt += 2) {
#pragma unroll
        for (int h = 0; h < 2; ++h) {
            const int tt = kt + h;                         // current K-tile
            const _Float16* abuf = lds + h * 32768 + (wm * 128) * 64;
            const _Float16* bbuf = lds + h * 32768 + 16384 + (wn * 64) * 64;

            // R0: all B frags + A frags for phase 0
            f16x8 bfrag[4][2];
            f16x8 afr[2][2][2];   // [parity][m2][kk]
#pragma unroll
            for (int n = 0; n < 4; ++n)
#pragma unroll
                for (int kk = 0; kk < 2; ++kk)
                    bfrag[n][kk] = *reinterpret_cast<const f16x8*>(
                        bbuf + (n * 16 + fr) * 64 + (swz ^ (kk << 5)));
#pragma unroll
            for (int m2 = 0; m2 < 2; ++m2)
#pragma unroll
                for (int kk = 0; kk < 2; ++kk)
                    afr[0][m2][kk] = *reinterpret_cast<const f16x8*>(
                        abuf + (m2 * 16 + fr) * 64 + (swz ^ (kk << 5)));

#pragma unroll
            for (int q = 0; q < 4; ++q) {
                // ---- read-ahead: A frags for phase q+1 ----
                if (q < 3) {
#pragma unroll
                    for (int m2 = 0; m2 < 2; ++m2)
#pragma unroll
                        for (int kk = 0; kk < 2; ++kk)
                            afr[(q + 1) & 1][m2][kk] = *reinterpret_cast<const f16x8*>(
                                abuf + ((q + 1) * 32 + m2 * 16 + fr) * 64 + (swz ^ (kk << 5)));
                }

                // ---- ring stages ----
                if (q == 0 && tt + 1 < NT) { STAGE_HT(h ^ 1, 0, tt + 1);
                                             STAGE_HT(h ^ 1, 1, tt + 1); }
                if (q == 1 && tt + 2 < NT) { STAGE_HT(h, 2, tt + 2); }
                if (q == 2 && tt + 2 < NT) { STAGE_HT(h, 3, tt + 2); }

                // ---- wait: phase-q frags ready (q+1's 4 reads may fly) ----
                if (q < 3) asm volatile("s_waitcnt lgkmcnt(4)" ::: "memory");
                else       asm volatile("s_waitcnt lgkmcnt(0)" ::: "memory");
                __builtin_amdgcn_sched_barrier(0);

                __builtin_amdgcn_s_setprio(1);
#pragma unroll
                for (int m2 = 0; m2 < 2; ++m2)
#pragma unroll
                    for (int n = 0; n < 4; ++n)
#pragma unroll
                        for (int kk = 0; kk < 2; ++kk)
                            acc[q * 2 + m2][n] = __builtin_amdgcn_mfma_f32_16x16x32_f16(
                                afr[q & 1][m2][kk], bfrag[n][kk], acc[q * 2 + m2][n], 0, 0, 0);
                __builtin_amdgcn_s_setprio(0);

                // ---- group end: counted vmcnt (never 0 in steady state) ----
                if (q == 3) {
                    if (tt + 2 < NT) asm volatile("s_waitcnt vmcnt(4)" ::: "memory");
                    else             asm volatile("s_waitcnt vmcnt(0)" ::: "memory");
                }
                BARRIER();
            }
        }
    }

    // ---- epilogue: C/D layout col=lane&15, row=(lane>>4)*4+j ----
    const float scale = beta_p[0] * gamma_p[0] * (1.0f / QBf);
    const int orow = bm + wm * 128 + lg * 4;
    const int ocol = bn + wn * 64 + fr;
#pragma unroll
    for (int m = 0; m < 8; ++m) {
#pragma unroll
        for (int j = 0; j < 4; ++j) {
            float* crow = C + (size_t)(orow + m * 16 + j) * N_DIM + ocol;
#pragma unroll
            for (int n = 0; n < 4; ++n)
                crow[n * 16] = acc[m][n][j] * scale;
        }
    }
#undef STAGE_HT
}

// ---------------------------------------------------------------------------
extern "C" void kernel_launch(void* const* d_in, const int* in_sizes, int n_in,
                              void* d_out, int out_size, void* d_ws, size_t ws_size,
                              hipStream_t stream)
{
    const float* x       = (const float*)d_in[0];
    const float* w       = (const float*)d_in[1];
    const float* ln_g    = (const float*)d_in[2];
    const float* ln_b    = (const float*)d_in[3];
    const float* beta_p  = (const float*)d_in[4];
    const float* gamma_p = (const float*)d_in[5];
    float* out = (float*)d_out;

    const int M = in_sizes[0] / K_DIM;   // 8192

    _Float16* xq = (_Float16*)d_ws;
    _Float16* wt = (_Float16*)((char*)d_ws + (size_t)M * K_DIM * sizeof(_Float16));

    ln_quant_kernel<<<M, 256, 0, stream>>>(x, ln_g, ln_b, gamma_p, xq);
    wtrans_kernel<<<dim3(N_DIM / 64, K_DIM / 64), 256, 0, stream>>>(w, wt);
    gemm_kernel<<<dim3(N_DIM / 256, M / 256), 512, 0, stream>>>(xq, wt, out, beta_p, gamma_p);
}

// Round 6
// 270.766 us; speedup vs baseline: 1.5614x; 1.0024x over previous
//
#include <hip/hip_runtime.h>
#include <hip/hip_fp16.h>

using f32x4 = __attribute__((ext_vector_type(4))) float;
using f16x8 = __attribute__((ext_vector_type(8))) _Float16;

constexpr int K_DIM = 4096;   // N_IN
constexpr int N_DIM = 4096;   // N_OUT
constexpr float QBf = 128.0f;
constexpr float EPf = 0.01f;
constexpr float LN_EPSf = 1e-5f;

#define GLOAD_LDS16(gp, lp)                                                  \
    __builtin_amdgcn_global_load_lds(                                        \
        (const __attribute__((address_space(1))) void*)(gp),                 \
        (__attribute__((address_space(3))) void*)(lp), 16, 0, 0)

#define BARRIER()                                                            \
    do { asm volatile("" ::: "memory");                                      \
         __builtin_amdgcn_s_barrier();                                       \
         asm volatile("" ::: "memory"); } while (0)

// ---------------------------------------------------------------------------
// Kernel 1: fused LayerNorm + ABSMax-quant + fp16 cast.  One block per row.
// ---------------------------------------------------------------------------
__global__ __launch_bounds__(256) void ln_quant_kernel(
    const float* __restrict__ x,
    const float* __restrict__ ln_g,
    const float* __restrict__ ln_b,
    const float* __restrict__ gamma_p,
    _Float16* __restrict__ xq)
{
    const int row = blockIdx.x;
    const int t = threadIdx.x;
    const float* xr = x + (size_t)row * K_DIM;

    float4 v[4];
    float sum = 0.f, sumsq = 0.f;
#pragma unroll
    for (int i = 0; i < 4; ++i) {
        v[i] = reinterpret_cast<const float4*>(xr)[i * 256 + t];
        sum += v[i].x + v[i].y + v[i].z + v[i].w;
        sumsq += v[i].x * v[i].x + v[i].y * v[i].y + v[i].z * v[i].z + v[i].w * v[i].w;
    }
#pragma unroll
    for (int off = 32; off > 0; off >>= 1) {
        sum += __shfl_down(sum, off);
        sumsq += __shfl_down(sumsq, off);
    }
    __shared__ float s_sum[4], s_sq[4];
    const int lane = t & 63, w = t >> 6;
    if (lane == 0) { s_sum[w] = sum; s_sq[w] = sumsq; }
    __syncthreads();
    sum = s_sum[0] + s_sum[1] + s_sum[2] + s_sum[3];
    sumsq = s_sq[0] + s_sq[1] + s_sq[2] + s_sq[3];

    const float mu = sum * (1.0f / K_DIM);
    const float var = sumsq * (1.0f / K_DIM) - mu * mu;
    const float rstd = rsqrtf(var + LN_EPSf);
    const float qs = QBf / gamma_p[0];
    const float lo = -QBf + EPf, hi = QBf - EPf;

    _Float16* xqr = xq + (size_t)row * K_DIM;
#pragma unroll
    for (int i = 0; i < 4; ++i) {
        const int idx = i * 256 + t;
        const float4 g = reinterpret_cast<const float4*>(ln_g)[idx];
        const float4 b = reinterpret_cast<const float4*>(ln_b)[idx];
        const float q0 = fminf(fmaxf(((v[i].x - mu) * rstd * g.x + b.x) * qs, lo), hi);
        const float q1 = fminf(fmaxf(((v[i].y - mu) * rstd * g.y + b.y) * qs, lo), hi);
        const float q2 = fminf(fmaxf(((v[i].z - mu) * rstd * g.z + b.z) * qs, lo), hi);
        const float q3 = fminf(fmaxf(((v[i].w - mu) * rstd * g.w + b.w) * qs, lo), hi);
        alignas(8) _Float16 h[4] = {(_Float16)q0, (_Float16)q1, (_Float16)q2, (_Float16)q3};
        *reinterpret_cast<uint2*>(xqr + (size_t)idx * 4) = *reinterpret_cast<const uint2*>(h);
    }
}

// ---------------------------------------------------------------------------
// Kernel 2: w (fp32, K x N, values ±1) -> wt (fp16, N x K).  64x64 LDS tiles.
// ---------------------------------------------------------------------------
__global__ __launch_bounds__(256) void wtrans_kernel(
    const float* __restrict__ w, _Float16* __restrict__ wt)
{
    __shared__ _Float16 tile[64][72];
    const int t = threadIdx.x;
    const int bk = blockIdx.y * 64;
    const int bn = blockIdx.x * 64;
#pragma unroll
    for (int i = 0; i < 4; ++i) {
        const int li = i * 1024 + t * 4;
        const int r = li >> 6, c = li & 63;
        const float4 vv = *reinterpret_cast<const float4*>(
            w + (size_t)(bk + r) * N_DIM + bn + c);
        tile[r][c]     = (_Float16)vv.x;
        tile[r][c + 1] = (_Float16)vv.y;
        tile[r][c + 2] = (_Float16)vv.z;
        tile[r][c + 3] = (_Float16)vv.w;
    }
    __syncthreads();
#pragma unroll
    for (int i = 0; i < 4; ++i) {
        const int li = i * 1024 + t * 4;
        const int r = li >> 6, c = li & 63;
        alignas(8) _Float16 h[4] = {tile[c][r], tile[c + 1][r], tile[c + 2][r], tile[c + 3][r]};
        *reinterpret_cast<uint2*>(wt + (size_t)(bn + r) * K_DIM + bk + c) =
            *reinterpret_cast<const uint2*>(h);
    }
}

// ---------------------------------------------------------------------------
// Kernel 3: GEMM  C[M,N] = A[M,K] * Bt[N,K]^T * scale   (fp16 MFMA, fp32 acc)
// 256x256 tile, BK=64, 512 threads = 8 waves (2M x 4N), wave tile 128x64.
// 4 sub-phases per K-tile, only TWO barriers per K-tile:
//   R0: read B frags (16) + A sub0 (4)
//   s0: read A sub1 | stage A(t+1)->buf^1 | lgkm(4) | 16 MFMA
//   s1: read A sub2 |                       lgkm(4) | 16 MFMA | BARRIER #1
//   s2: read A sub3 | stage B(t+2)->buf   | lgkm(4) | 16 MFMA
//   s3:                                     lgkm(0) | 16 MFMA | vmcnt(4) | BARRIER #2
// Safety: A(t+1) stage safe after prev tile's final barrier (all A(t-1) reads
// done by prev lgkm(0)); B(t+2) stage at s2 safe after BARRIER #1 (every
// wave's B(t) reads completed before its own s0-lgkm(4), hence before #1).
// vmcnt(4) at s3 leaves B(t+2)'s 4 loads in flight (never drains to 0).
// Staging addresses: one per-lane byte voffset precomputed; per call is
// uniform-base + scalar offset (+524288 for the second 64-row round).
// T1 XCD block swizzle; T2 XOR chunk swizzle on stage-source and read side.
// ---------------------------------------------------------------------------
__global__ __launch_bounds__(512, 2) void gemm_kernel(
    const _Float16* __restrict__ A,
    const _Float16* __restrict__ Bt,
    float* __restrict__ C,
    const float* __restrict__ beta_p,
    const float* __restrict__ gamma_p)
{
    constexpr int NT = K_DIM / 64;                 // 64 K-tiles
    __shared__ _Float16 lds[65536];                // 128 KiB: [buf][A|B][256][64]

    const int t = threadIdx.x;
    // ---- XCD swizzle: flat id -> 8x8 square per XCD (512 blocks, 16x32 grid)
    const int flat = blockIdx.y * gridDim.x + blockIdx.x;
    const int xcd = flat & 7;
    const int r8 = flat >> 3;                       // 0..63
    const int by = ((xcd >> 1) << 3) + (r8 >> 3);   // 0..31  (M index)
    const int bx = ((xcd & 1) << 3) + (r8 & 7);     // 0..15  (N index)
    const int bm = by * 256;
    const int bn = bx * 256;

    const int lane = t & 63;
    const int w = t >> 6;
    const int wm = w >> 2;            // 0..1
    const int wn = w & 3;             // 0..3
    const int fr = lane & 15;
    const int lg = lane >> 4;         // 0..3
    const int swz = ((lg ^ (fr & 7)) << 3);   // halfs; kk=1 -> swz ^ 32

    const char* gA = (const char*)A + (size_t)bm * K_DIM * 2;
    const char* gB = (const char*)Bt + (size_t)bn * K_DIM * 2;
    char* ldsb = (char*)lds;
    // per-lane staging byte offset (row r0 = t>>3, chunk j0 = t&7, swizzled)
    const int voff = ((t >> 3) << 13) + (((t & 7) ^ ((t >> 3) & 7)) << 4);

    // stage half-tile ht (0=Ah0,1=Ah1,2=Bh0,3=Bh1) of K-tile kt into buffer b
#define STAGE_HT(b, ht, kt)                                                   \
    do {                                                                      \
        const char* g0 = (((ht) < 2) ? gA : gB)                               \
                         + (size_t)(((ht) & 1) * 1048576 + (kt) * 128);       \
        char* l0 = ldsb + ((b) * 65536 + (((ht) < 2) ? 0 : 32768)             \
                          + ((ht) & 1) * 16384) + t * 16;                     \
        GLOAD_LDS16(g0 + voff, l0);                                           \
        GLOAD_LDS16(g0 + 524288 + voff, l0 + 8192);                           \
    } while (0)

#define READ_A(par, sub)                                                      \
    _Pragma("unroll")                                                         \
    for (int m2 = 0; m2 < 2; ++m2)                                            \
        _Pragma("unroll")                                                     \
        for (int kk = 0; kk < 2; ++kk)                                        \
            afr[par][m2][kk] = *reinterpret_cast<const f16x8*>(               \
                abuf + ((sub) * 32 + m2 * 16 + fr) * 64 + (swz ^ (kk << 5)));

#define MFMA_SUB(par, sub)                                                    \
    do {                                                                      \
        __builtin_amdgcn_s_setprio(1);                                        \
        _Pragma("unroll")                                                     \
        for (int m2 = 0; m2 < 2; ++m2)                                        \
            _Pragma("unroll")                                                 \
            for (int n = 0; n < 4; ++n)                                       \
                _Pragma("unroll")                                             \
                for (int kk = 0; kk < 2; ++kk)                                \
                    acc[(sub) * 2 + m2][n] =                                  \
                        __builtin_amdgcn_mfma_f32_16x16x32_f16(               \
                            afr[par][m2][kk], bfrag[n][kk],                   \
                            acc[(sub) * 2 + m2][n], 0, 0, 0);                 \
        __builtin_amdgcn_s_setprio(0);                                        \
    } while (0)

#define WAIT_LGKM(N)                                                          \
    do { asm volatile("s_waitcnt lgkmcnt(" #N ")" ::: "memory");              \
         __builtin_amdgcn_sched_barrier(0); } while (0)

    f32x4 acc[8][4];
#pragma unroll
    for (int m = 0; m < 8; ++m)
#pragma unroll
        for (int n = 0; n < 4; ++n)
            acc[m][n] = (f32x4){0.f, 0.f, 0.f, 0.f};

    // prologue: A(0),B(0) -> buf0; B(1) -> buf1; wait all but B(1); sync
    STAGE_HT(0, 0, 0); STAGE_HT(0, 1, 0); STAGE_HT(0, 2, 0); STAGE_HT(0, 3, 0);
    STAGE_HT(1, 2, 1); STAGE_HT(1, 3, 1);
    asm volatile("s_waitcnt vmcnt(4)" ::: "memory");
    BARRIER();

    for (int kt = 0; kt < NT; kt += 2) {
#pragma unroll
        for (int h = 0; h < 2; ++h) {
            const int tt = kt + h;                         // current K-tile
            const _Float16* abuf = lds + h * 32768 + (wm * 128) * 64;
            const _Float16* bbuf = lds + h * 32768 + 16384 + (wn * 64) * 64;

            f16x8 bfrag[4][2];
            f16x8 afr[2][2][2];   // [parity][m2][kk]

            // ---- R0: all B frags + A sub0 ----
#pragma unroll
            for (int n = 0; n < 4; ++n)
#pragma unroll
                for (int kk = 0; kk < 2; ++kk)
                    bfrag[n][kk] = *reinterpret_cast<const f16x8*>(
                        bbuf + (n * 16 + fr) * 64 + (swz ^ (kk << 5)));
            READ_A(0, 0);

            // ---- s0 ----
            READ_A(1, 1);
            if (tt + 1 < NT) { STAGE_HT(h ^ 1, 0, tt + 1); STAGE_HT(h ^ 1, 1, tt + 1); }
            WAIT_LGKM(4);
            MFMA_SUB(0, 0);

            // ---- s1 ----
            READ_A(0, 2);
            WAIT_LGKM(4);
            MFMA_SUB(1, 1);
            BARRIER();                                     // B(t) reads done chip-wide

            // ---- s2 ----
            READ_A(1, 3);
            if (tt + 2 < NT) { STAGE_HT(h, 2, tt + 2); STAGE_HT(h, 3, tt + 2); }
            WAIT_LGKM(4);
            MFMA_SUB(0, 2);

            // ---- s3 ----
            WAIT_LGKM(0);
            MFMA_SUB(1, 3);
            if (tt + 2 < NT) asm volatile("s_waitcnt vmcnt(4)" ::: "memory");
            else             asm volatile("s_waitcnt vmcnt(0)" ::: "memory");
            BARRIER();                                     // next tile ready
        }
    }

    // ---- epilogue: C/D layout col=lane&15, row=(lane>>4)*4+j ----
    const float scale = beta_p[0] * gamma_p[0] * (1.0f / QBf);
    const int orow = bm + wm * 128 + lg * 4;
    const int ocol = bn + wn * 64 + fr;
#pragma unroll
    for (int m = 0; m < 8; ++m) {
#pragma unroll
        for (int j = 0; j < 4; ++j) {
            float* crow = C + (size_t)(orow + m * 16 + j) * N_DIM + ocol;
#pragma unroll
            for (int n = 0; n < 4; ++n)
                crow[n * 16] = acc[m][n][j] * scale;
        }
    }
#undef STAGE_HT
#undef READ_A
#undef MFMA_SUB
#undef WAIT_LGKM
}

// ---------------------------------------------------------------------------
extern "C" void kernel_launch(void* const* d_in, const int* in_sizes, int n_in,
                              void* d_out, int out_size, void* d_ws, size_t ws_size,
                              hipStream_t stream)
{
    const float* x       = (const float*)d_in[0];
    const float* w       = (const float*)d_in[1];
    const float* ln_g    = (const float*)d_in[2];
    const float* ln_b    = (const float*)d_in[3];
    const float* beta_p  = (const float*)d_in[4];
    const float* gamma_p = (const float*)d_in[5];
    float* out = (float*)d_out;

    const int M = in_sizes[0] / K_DIM;   // 8192

    _Float16* xq = (_Float16*)d_ws;
    _Float16* wt = (_Float16*)((char*)d_ws + (size_t)M * K_DIM * sizeof(_Float16));

    ln_quant_kernel<<<M, 256, 0, stream>>>(x, ln_g, ln_b, gamma_p, xq);
    wtrans_kernel<<<dim3(N_DIM / 64, K_DIM / 64), 256, 0, stream>>>(w, wt);
    gemm_kernel<<<dim3(N_DIM / 256, M / 256), 512, 0, stream>>>(xq, wt, out, beta_p, gamma_p);
}

// Round 7
// 232.341 us; speedup vs baseline: 1.8197x; 1.1654x over previous
//
#include <hip/hip_runtime.h>

using f32x4  = __attribute__((ext_vector_type(4))) float;
using i32x4  = __attribute__((ext_vector_type(4))) int;
using i32x16 = __attribute__((ext_vector_type(16))) int;

constexpr int K_DIM = 4096;   // N_IN
constexpr int N_DIM = 4096;   // N_OUT
constexpr float QBf = 128.0f;
constexpr float EPf = 0.01f;
constexpr float LN_EPSf = 1e-5f;

#define GLOAD_LDS16(gp, lp)                                                  \
    __builtin_amdgcn_global_load_lds(                                        \
        (const __attribute__((address_space(1))) void*)(gp),                 \
        (__attribute__((address_space(3))) void*)(lp), 16, 0, 0)

#define BARRIER()                                                            \
    do { asm volatile("" ::: "memory");                                      \
         __builtin_amdgcn_s_barrier();                                       \
         asm volatile("" ::: "memory"); } while (0)

#define WAIT_LGKM(N)                                                         \
    do { asm volatile("s_waitcnt lgkmcnt(" #N ")" ::: "memory");             \
         __builtin_amdgcn_sched_barrier(0); } while (0)

// ---------------------------------------------------------------------------
// Kernel 1: fused LayerNorm + ABSMax-quant + round-to-int8.  One block/row.
// Each thread handles 16 consecutive elements.
// ---------------------------------------------------------------------------
__global__ __launch_bounds__(256) void ln_quant_kernel(
    const float* __restrict__ x,
    const float* __restrict__ ln_g,
    const float* __restrict__ ln_b,
    const float* __restrict__ gamma_p,
    char* __restrict__ xq)
{
    const int row = blockIdx.x;
    const int t = threadIdx.x;
    const float4* xr4 = reinterpret_cast<const float4*>(x + (size_t)row * K_DIM);

    float4 v[4];
    float sum = 0.f, sumsq = 0.f;
#pragma unroll
    for (int i = 0; i < 4; ++i) {
        v[i] = xr4[t * 4 + i];
        sum += v[i].x + v[i].y + v[i].z + v[i].w;
        sumsq += v[i].x * v[i].x + v[i].y * v[i].y + v[i].z * v[i].z + v[i].w * v[i].w;
    }
#pragma unroll
    for (int off = 32; off > 0; off >>= 1) {
        sum += __shfl_down(sum, off);
        sumsq += __shfl_down(sumsq, off);
    }
    __shared__ float s_sum[4], s_sq[4];
    const int lane = t & 63, w = t >> 6;
    if (lane == 0) { s_sum[w] = sum; s_sq[w] = sumsq; }
    __syncthreads();
    sum = s_sum[0] + s_sum[1] + s_sum[2] + s_sum[3];
    sumsq = s_sq[0] + s_sq[1] + s_sq[2] + s_sq[3];

    const float mu = sum * (1.0f / K_DIM);
    const float var = sumsq * (1.0f / K_DIM) - mu * mu;
    const float rstd = rsqrtf(var + LN_EPSf);
    const float qs = QBf / gamma_p[0];
    const float lo = -QBf + EPf, hi = QBf - EPf;

    alignas(16) char ob[16];
#pragma unroll
    for (int i = 0; i < 4; ++i) {
        const float4 g = reinterpret_cast<const float4*>(ln_g)[t * 4 + i];
        const float4 b = reinterpret_cast<const float4*>(ln_b)[t * 4 + i];
        const float f0 = fminf(fmaxf(((v[i].x - mu) * rstd * g.x + b.x) * qs, lo), hi);
        const float f1 = fminf(fmaxf(((v[i].y - mu) * rstd * g.y + b.y) * qs, lo), hi);
        const float f2 = fminf(fmaxf(((v[i].z - mu) * rstd * g.z + b.z) * qs, lo), hi);
        const float f3 = fminf(fmaxf(((v[i].w - mu) * rstd * g.w + b.w) * qs, lo), hi);
        int x0 = (int)rintf(f0), x1 = (int)rintf(f1);
        int x2 = (int)rintf(f2), x3 = (int)rintf(f3);
        ob[i * 4 + 0] = (char)(x0 > 127 ? 127 : x0);
        ob[i * 4 + 1] = (char)(x1 > 127 ? 127 : x1);
        ob[i * 4 + 2] = (char)(x2 > 127 ? 127 : x2);
        ob[i * 4 + 3] = (char)(x3 > 127 ? 127 : x3);
    }
    *reinterpret_cast<uint4*>(xq + (size_t)row * K_DIM + t * 16) =
        *reinterpret_cast<const uint4*>(ob);
}

// ---------------------------------------------------------------------------
// Kernel 2: w (fp32, K x N, values ±1) -> wq (int8, N x K).  64x64 tiles.
// ---------------------------------------------------------------------------
__global__ __launch_bounds__(256) void wtrans_kernel(
    const float* __restrict__ w, char* __restrict__ wq)
{
    __shared__ char tile[64][68];
    const int t = threadIdx.x;
    const int bk = blockIdx.y * 64;
    const int bn = blockIdx.x * 64;
#pragma unroll
    for (int i = 0; i < 4; ++i) {
        const int li = i * 1024 + t * 4;
        const int r = li >> 6, c = li & 63;    // r = k-in-tile, c = n-in-tile
        const float4 vv = *reinterpret_cast<const float4*>(
            w + (size_t)(bk + r) * N_DIM + bn + c);
        tile[r][c]     = (char)vv.x;
        tile[r][c + 1] = (char)vv.y;
        tile[r][c + 2] = (char)vv.z;
        tile[r][c + 3] = (char)vv.w;
    }
    __syncthreads();
    const int n = t >> 2, kc = t & 3;
    alignas(16) char h16[16];
#pragma unroll
    for (int j = 0; j < 16; ++j) h16[j] = tile[kc * 16 + j][n];
    *reinterpret_cast<uint4*>(wq + (size_t)(bn + n) * K_DIM + bk + kc * 16) =
        *reinterpret_cast<const uint4*>(h16);
}

// ---------------------------------------------------------------------------
// Kernel 3: GEMM  C[M,N] = A[M,K] * Bt[N,K]^T * scale  (i8 MFMA, i32 acc)
// 256x256 tile, BK=64 (bytes), 512 threads = 8 waves (2M x 4N),
// wave tile 128x64 as 4x2 frags of mfma_i32_32x32x32_i8 (2 k-steps/K-tile).
// LDS K-block layout per 128-row half: [kc 0..3][row 0..127][16B]  -- the
// natural slot order IS linear (slot = t), so global_load_lds dest stays
// linear and every 32-lane fragment read is 512 contiguous bytes: zero
// bank conflicts by construction, no XOR swizzle needed.
// Schedule (per K-tile, 2 barriers, counted waits; ring identical to R6):
//   R0: read bfrag x4 + afr(s0) x2
//   s0: read afr(s1) | stage A(t+1)->buf^1 | lgkm(2) | 4 MFMA
//   s1: read afr(s2) |                       lgkm(2) | 4 MFMA | BARRIER #1
//   s2: read afr(s3) | stage B(t+2)->buf   | lgkm(2) | 4 MFMA
//   s3:                                      lgkm(0) | 4 MFMA | vmcnt(2) | BARRIER #2
// vmcnt(2) forces A(t+1),B(t+1) landed, leaves B(t+2) in flight.
// ---------------------------------------------------------------------------
__global__ __launch_bounds__(512, 2) void gemm_kernel(
    const char* __restrict__ A,
    const char* __restrict__ Bt,
    float* __restrict__ C,
    const float* __restrict__ beta_p,
    const float* __restrict__ gamma_p)
{
    constexpr int NT = K_DIM / 64;                 // 64 K-tiles
    __shared__ __align__(16) char lds[65536];      // 2 bufs x (A 16K | B 16K)

    const int t = threadIdx.x;
    // ---- XCD swizzle: flat id -> 8x8 square per XCD (512 blocks, 16x32 grid)
    const int flat = blockIdx.y * gridDim.x + blockIdx.x;
    const int xcd = flat & 7;
    const int r8 = flat >> 3;                       // 0..63
    const int by = ((xcd >> 1) << 3) + (r8 >> 3);   // 0..31  (M index)
    const int bx = ((xcd & 1) << 3) + (r8 & 7);     // 0..15  (N index)
    const int bm = by * 256;
    const int bn = bx * 256;

    const int lane = t & 63;
    const int w = t >> 6;
    const int wm = w >> 2;            // 0..1
    const int wn = w & 3;             // 0..3
    const int ln31 = lane & 31;
    const int lg2 = lane >> 5;        // 0..1

    const char* gA = A + (size_t)bm * K_DIM;
    const char* gB = Bt + (size_t)bn * K_DIM;
    // per-lane staging source offset: row (t&127), k-chunk (t>>7)
    const int voff = (t & 127) * K_DIM + (t >> 7) * 16;

    // per-lane fragment read offsets within a 128-row half region
    const int aoff = lg2 * 2048 + ln31 * 16;
    const int boff = lg2 * 2048 + ((wn & 1) * 64 + ln31) * 16;

    // stage half-tile ht (0=Ah0,1=Ah1,2=Bh0,3=Bh1) of K-tile kt into buffer b
#define STAGE_HT(b, ht, kt)                                                   \
    GLOAD_LDS16((((ht) < 2) ? gA : gB)                                        \
                    + (size_t)(((ht) & 1) * (128 * K_DIM) + (kt) * 64) + voff,\
                lds + (b) * 32768 + (((ht) < 2) ? 0 : 16384)                  \
                    + ((ht) & 1) * 8192 + t * 16)

#define READ_A(par, ks, mfp)                                                  \
    do {                                                                      \
        afr[par][0] = *reinterpret_cast<const i32x4*>(                        \
            abase + (ks) * 4096 + ((mfp) * 2) * 512 + aoff);                  \
        afr[par][1] = *reinterpret_cast<const i32x4*>(                        \
            abase + (ks) * 4096 + ((mfp) * 2 + 1) * 512 + aoff);              \
    } while (0)

#define MFMA4(par, ks, mfp)                                                   \
    do {                                                                      \
        __builtin_amdgcn_s_setprio(1);                                        \
        _Pragma("unroll")                                                     \
        for (int m2 = 0; m2 < 2; ++m2)                                        \
            _Pragma("unroll")                                                 \
            for (int nf = 0; nf < 2; ++nf)                                    \
                acc[(mfp) * 2 + m2][nf] =                                     \
                    __builtin_amdgcn_mfma_i32_32x32x32_i8(                    \
                        afr[par][m2], bfrag[nf][ks],                          \
                        acc[(mfp) * 2 + m2][nf], 0, 0, 0);                    \
        __builtin_amdgcn_s_setprio(0);                                        \
    } while (0)

    i32x16 acc[4][2];
#pragma unroll
    for (int m = 0; m < 4; ++m)
#pragma unroll
        for (int n = 0; n < 2; ++n)
#pragma unroll
            for (int r = 0; r < 16; ++r)
                acc[m][n][r] = 0;

    // prologue: A(0),B(0) -> buf0; B(1) -> buf1; wait all but B(1); sync
    STAGE_HT(0, 0, 0); STAGE_HT(0, 1, 0); STAGE_HT(0, 2, 0); STAGE_HT(0, 3, 0);
    STAGE_HT(1, 2, 1); STAGE_HT(1, 3, 1);
    asm volatile("s_waitcnt vmcnt(2)" ::: "memory");
    BARRIER();

    for (int kt = 0; kt < NT; kt += 2) {
#pragma unroll
        for (int h = 0; h < 2; ++h) {
            const int tt = kt + h;                         // current K-tile
            const char* abase = lds + h * 32768 + wm * 8192;
            const char* bbase = lds + h * 32768 + 16384 + (wn >> 1) * 8192;

            i32x4 bfrag[2][2];   // [nf][ks]
            i32x4 afr[2][2];     // [parity][m2]

            // ---- R0: all B frags + A frags for s0 ----
#pragma unroll
            for (int nf = 0; nf < 2; ++nf)
#pragma unroll
                for (int ks = 0; ks < 2; ++ks)
                    bfrag[nf][ks] = *reinterpret_cast<const i32x4*>(
                        bbase + ks * 4096 + nf * 512 + boff);
            READ_A(0, 0, 0);

            // ---- s0 ----
            READ_A(1, 0, 1);
            if (tt + 1 < NT) { STAGE_HT(h ^ 1, 0, tt + 1); STAGE_HT(h ^ 1, 1, tt + 1); }
            WAIT_LGKM(2);
            MFMA4(0, 0, 0);

            // ---- s1 ----
            READ_A(0, 1, 0);
            WAIT_LGKM(2);
            MFMA4(1, 0, 1);
            BARRIER();                                     // B(t) reads done

            // ---- s2 ----
            READ_A(1, 1, 1);
            if (tt + 2 < NT) { STAGE_HT(h, 2, tt + 2); STAGE_HT(h, 3, tt + 2); }
            WAIT_LGKM(2);
            MFMA4(0, 1, 0);

            // ---- s3 ----
            WAIT_LGKM(0);
            MFMA4(1, 1, 1);
            if (tt + 2 < NT) asm volatile("s_waitcnt vmcnt(2)" ::: "memory");
            else             asm volatile("s_waitcnt vmcnt(0)" ::: "memory");
            BARRIER();                                     // next tile ready
        }
    }

    // ---- epilogue: 32x32 C/D layout: col=lane&31,
    //      row = (reg&3) + 8*(reg>>2) + 4*(lane>>5) ----
    const float scale = beta_p[0] * gamma_p[0] * (1.0f / QBf);
    const int orow0 = bm + wm * 128 + lg2 * 4;
    const int ocol0 = bn + wn * 64 + ln31;
#pragma unroll
    for (int mf = 0; mf < 4; ++mf) {
#pragma unroll
        for (int nf = 0; nf < 2; ++nf) {
#pragma unroll
            for (int reg = 0; reg < 16; ++reg) {
                const int row = orow0 + mf * 32 + (reg & 3) + 8 * (reg >> 2);
                C[(size_t)row * N_DIM + ocol0 + nf * 32] =
                    (float)acc[mf][nf][reg] * scale;
            }
        }
    }
#undef STAGE_HT
#undef READ_A
#undef MFMA4
}

// ---------------------------------------------------------------------------
extern "C" void kernel_launch(void* const* d_in, const int* in_sizes, int n_in,
                              void* d_out, int out_size, void* d_ws, size_t ws_size,
                              hipStream_t stream)
{
    const float* x       = (const float*)d_in[0];
    const float* w       = (const float*)d_in[1];
    const float* ln_g    = (const float*)d_in[2];
    const float* ln_b    = (const float*)d_in[3];
    const float* beta_p  = (const float*)d_in[4];
    const float* gamma_p = (const float*)d_in[5];
    float* out = (float*)d_out;

    const int M = in_sizes[0] / K_DIM;   // 8192

    char* xq = (char*)d_ws;
    char* wq = (char*)d_ws + (size_t)M * K_DIM;

    ln_quant_kernel<<<M, 256, 0, stream>>>(x, ln_g, ln_b, gamma_p, xq);
    wtrans_kernel<<<dim3(N_DIM / 64, K_DIM / 64), 256, 0, stream>>>(w, wq);
    gemm_kernel<<<dim3(N_DIM / 256, M / 256), 512, 0, stream>>>(xq, wq, out, beta_p, gamma_p);
}